// Round 11
// baseline (616.741 us; speedup 1.0000x reference)
//
#include <hip/hip_runtime.h>

#define N_PTS   1000000
#define N_TILES 15625
#define NBKT    32768

typedef _Float16 f16;
typedef _Float16 f16x2 __attribute__((ext_vector_type(2)));
typedef _Float16 f16x8 __attribute__((ext_vector_type(8)));
typedef float    f32x4 __attribute__((ext_vector_type(4)));

// ws layout (f16 elements), planes channel-last [H][W][32]
#define PXY_C 0
#define PXZ_C 524288
#define PYZ_C 1048576
#define PXY_F 1572864
#define PXZ_F 9961472
#define PYZ_F 18350080
#define PCXY  26738688
#define PCXZ  28835840
#define PCYZ  30932992
#define WBOFF 33030144
#define FIXED_BYTES ((size_t)(WBOFF + 40960) * 2)   // 66,142,208
// sort region (byte offsets from ws base)
#define HIST_B  66142208u
#define CURS_B  (HIST_B + 131072u)
#define SIDX_B  (HIST_B + 262144u)
#define SXYZ_B  (SIDX_B + 4000000u)
#define SORT_END (SXYZ_B + 12000000u)               // 82,404,352

__device__ __forceinline__ f32x4 mfma16(f16x8 a, f16x8 b, f32x4 c) {
    return __builtin_amdgcn_mfma_f32_16x16x32_f16(a, b, c, 0, 0, 0);
}

#define LDS_FENCE() asm volatile("s_waitcnt lgkmcnt(0)" ::: "memory")

// ---- merged pre-pass: all 9 planes [32,H,W] f32 -> [H,W,32] f16
__global__ __launch_bounds__(256) void transpose_all(
    const float* __restrict__ s0, const float* __restrict__ s1, const float* __restrict__ s2,
    const float* __restrict__ s3, const float* __restrict__ s4, const float* __restrict__ s5,
    const float* __restrict__ s6, const float* __restrict__ s7, const float* __restrict__ s8,
    unsigned short* __restrict__ ws) {
    const int b = blockIdx.x;
    const float* src;
    int npix;
    size_t doff;
    int pix0;
    if (b < 192) {                       // coarse: 3 x 64 blocks
        const int pl = b >> 6;
        src = pl == 0 ? s0 : (pl == 1 ? s1 : s2);
        npix = 16384; doff = (size_t)pl * 524288; pix0 = (b & 63) * 256;
    } else if (b < 3264) {               // fine: 3 x 1024 blocks
        const int t = b - 192, pl = t >> 10;
        src = pl == 0 ? s3 : (pl == 1 ? s4 : s5);
        npix = 262144; doff = 1572864 + (size_t)pl * 8388608; pix0 = (t & 1023) * 256;
    } else {                             // color: 3 x 256 blocks
        const int t = b - 3264, pl = t >> 8;
        src = pl == 0 ? s6 : (pl == 1 ? s7 : s8);
        npix = 65536; doff = 26738688 + (size_t)pl * 2097152; pix0 = (t & 255) * 256;
    }
    const int pix = pix0 + threadIdx.x;
    unsigned w[16];
#pragma unroll
    for (int j = 0; j < 16; ++j) {
        f16x2 v = { (f16)src[(size_t)(2*j) * npix + pix], (f16)src[(size_t)(2*j+1) * npix + pix] };
        w[j] = __builtin_bit_cast(unsigned, v);
    }
    unsigned short* dst = ws + doff + (size_t)pix * 32;
#pragma unroll
    for (int j = 0; j < 4; ++j) {
        uint4 o; o.x = w[4*j+0]; o.y = w[4*j+1]; o.z = w[4*j+2]; o.w = w[4*j+3];
        *(uint4*)(dst + 8*j) = o;
    }
}

// ---- merged pre-pass: all 6 weight matrices f32 -> f16 (dst contiguous)
__global__ __launch_bounds__(256) void weights_all(
    const float* __restrict__ w0, const float* __restrict__ w1, const float* __restrict__ w2,
    const float* __restrict__ w3, const float* __restrict__ w4, const float* __restrict__ w5,
    unsigned short* __restrict__ dst) {
    const int u = blockIdx.x * 256 + threadIdx.x;   // [0, 40960)
    const float* src;
    int local;
    if (u < 2048)       { src = w0; local = u; }
    else if (u < 6144)  { src = w1; local = u - 2048; }
    else if (u < 18432) { src = w2; local = u - 6144; }
    else if (u < 34816) { src = w3; local = u - 18432; }
    else if (u < 36864) { src = w4; local = u - 34816; }
    else                { src = w5; local = u - 36864; }
    f16 h = (f16)src[local];
    dst[u] = __builtin_bit_cast(unsigned short, h);
}

// ---- Morton key (5 bits/axis, 32^3 cells)
__device__ __forceinline__ unsigned mpart5(unsigned v) {
    v &= 31u;
    v = (v | (v << 8)) & 0x100Fu;
    v = (v | (v << 4)) & 0x10C3u;
    v = (v | (v << 2)) & 0x1249u;
    return v;
}
__device__ __forceinline__ int morton_key(float x, float y, float z) {
    int gx = min(max((int)((x + 1.0f) * 16.0f), 0), 31);
    int gy = min(max((int)((y + 1.0f) * 16.0f), 0), 31);
    int gz = min(max((int)((z + 1.0f) * 16.0f), 0), 31);
    return (int)(mpart5((unsigned)gx) | (mpart5((unsigned)gy) << 1) | (mpart5((unsigned)gz) << 2));
}

__global__ __launch_bounds__(256) void hist_kernel(const float* __restrict__ p, int* __restrict__ hist) {
    int i = blockIdx.x * 256 + threadIdx.x;
    if (i >= N_PTS) return;
    atomicAdd(&hist[morton_key(p[3*(size_t)i], p[3*(size_t)i+1], p[3*(size_t)i+2])], 1);
}

__global__ __launch_bounds__(1024) void scan_kernel(const int* __restrict__ hist, int* __restrict__ cursor) {
    __shared__ int psum[1024];
    const int t = threadIdx.x;
    int s = 0;
    for (int j = 0; j < 32; ++j) s += hist[t * 32 + j];
    psum[t] = s;
    __syncthreads();
    for (int off = 1; off < 1024; off <<= 1) {
        int v = (t >= off) ? psum[t - off] : 0;
        __syncthreads();
        psum[t] += v;
        __syncthreads();
    }
    int run = (t > 0) ? psum[t - 1] : 0;
    for (int j = 0; j < 32; ++j) {
        const int idx = t * 32 + j;
        cursor[idx] = run;
        run += hist[idx];
    }
}

__global__ __launch_bounds__(256) void scatter_kernel(const float* __restrict__ p, int* __restrict__ cursor,
                                                      float* __restrict__ sxyz, int* __restrict__ sidx) {
    int i = blockIdx.x * 256 + threadIdx.x;
    if (i >= N_PTS) return;
    const float x = p[3*(size_t)i], y = p[3*(size_t)i+1], z = p[3*(size_t)i+2];
    const int pos = atomicAdd(&cursor[morton_key(x, y, z)], 1);
    sxyz[3*(size_t)pos]   = x;
    sxyz[3*(size_t)pos+1] = y;
    sxyz[3*(size_t)pos+2] = z;
    sidx[pos] = i;
}

// ---- coalesced 3-plane bilinear gather, one 64-pt tile (proven math).
template <int SW>
__device__ __forceinline__ void gather3(
    const unsigned short* __restrict__ P0, const unsigned short* __restrict__ P1,
    const unsigned short* __restrict__ P2, int R,
    const float* __restrict__ p, int ptbase, int lane, char* dst) {
    const int sub = lane >> 2, ch = lane & 3;
    const float Rs = 0.5f * (float)(R - 1);
#pragma unroll
    for (int r = 0; r < 4; ++r) {
        const int row = r * 16 + sub;
        const float* pp = p + 3 * (size_t)(ptbase + row);
        const float pa = pp[0], pb = pp[1], pc = pp[2];
        f16x2 a0 = {0,0}, a1 = {0,0}, a2 = {0,0}, a3 = {0,0};
        const float cA[3] = {pa, pa, pb};
        const float cB[3] = {pb, pc, pc};
        const unsigned short* tp[3] = {P0, P1, P2};
#pragma unroll
        for (int pl = 0; pl < 3; ++pl) {
            float x = (cA[pl] + 1.0f) * Rs;
            float y = (cB[pl] + 1.0f) * Rs;
            float fx = floorf(x), fy = floorf(y);
            float wx = x - fx, wy = y - fy;
            int x0 = min(max((int)fx, 0), R - 1);
            int x1 = min(x0 + 1, R - 1);
            int y0 = min(max((int)fy, 0), R - 1);
            int y1 = min(y0 + 1, R - 1);
            const unsigned short* b = tp[pl];
            uint4 v00 = *(const uint4*)(b + (size_t)(y0 * R + x0) * 32 + ch * 8);
            uint4 v01 = *(const uint4*)(b + (size_t)(y0 * R + x1) * 32 + ch * 8);
            uint4 v10 = *(const uint4*)(b + (size_t)(y1 * R + x0) * 32 + ch * 8);
            uint4 v11 = *(const uint4*)(b + (size_t)(y1 * R + x1) * 32 + ch * 8);
            f16 h00 = (f16)((1.0f - wx) * (1.0f - wy));
            f16 h01 = (f16)(wx * (1.0f - wy));
            f16 h10 = (f16)((1.0f - wx) * wy);
            f16 h11 = (f16)(wx * wy);
            f16x2 w00 = {h00, h00}, w01 = {h01, h01}, w10 = {h10, h10}, w11 = {h11, h11};
            a0 += __builtin_bit_cast(f16x2, v00.x) * w00 + __builtin_bit_cast(f16x2, v01.x) * w01
                + __builtin_bit_cast(f16x2, v10.x) * w10 + __builtin_bit_cast(f16x2, v11.x) * w11;
            a1 += __builtin_bit_cast(f16x2, v00.y) * w00 + __builtin_bit_cast(f16x2, v01.y) * w01
                + __builtin_bit_cast(f16x2, v10.y) * w10 + __builtin_bit_cast(f16x2, v11.y) * w11;
            a2 += __builtin_bit_cast(f16x2, v00.z) * w00 + __builtin_bit_cast(f16x2, v01.z) * w01
                + __builtin_bit_cast(f16x2, v10.z) * w10 + __builtin_bit_cast(f16x2, v11.z) * w11;
            a3 += __builtin_bit_cast(f16x2, v00.w) * w00 + __builtin_bit_cast(f16x2, v01.w) * w01
                + __builtin_bit_cast(f16x2, v10.w) * w10 + __builtin_bit_cast(f16x2, v11.w) * w11;
        }
        uint4 o;
        o.x = __builtin_bit_cast(unsigned, a0);
        o.y = __builtin_bit_cast(unsigned, a1);
        o.z = __builtin_bit_cast(unsigned, a2);
        o.w = __builtin_bit_cast(unsigned, a3);
        *(uint4*)(dst + row * 64 + ((ch * 16) ^ ((row & SW) << 4))) = o;
    }
}

// A-frag loads from swizzled LDS
template <int KT, int SWA>
__device__ __forceinline__ void ldA(f16x8 (&A)[4][KT], const char* src, int RSb, int c0, int q0) {
#pragma unroll
    for (int mt = 0; mt < 4; ++mt) {
        const int row = 16 * mt + c0;
#pragma unroll
        for (int ks = 0; ks < KT; ++ks)
            A[mt][ks] = *(const f16x8*)(src + row * RSb + ((16*q0 + 64*ks) ^ ((row & SWA) << 4)));
    }
}

// GEMM: A (regs) x W[N][K] (global f16) -> relu -> LDS, swizzle (row&7)<<4
template <int KT, int NT>
__device__ __forceinline__ void gemm_store(const f16x8 (&A)[4][KT], char* O, int RSOb,
                                           const unsigned short* __restrict__ Wg, int K,
                                           const float* __restrict__ bias, int c0, int q0) {
#pragma unroll
    for (int nt = 0; nt < NT; ++nt) {
        f16x8 B[KT];
#pragma unroll
        for (int ks = 0; ks < KT; ++ks)
            B[ks] = *(const f16x8*)(Wg + (size_t)(16*nt + c0) * K + 8*q0 + 32*ks);
        const float bv = bias[16*nt + c0];
#pragma unroll
        for (int mt = 0; mt < 4; ++mt) {
            f32x4 acc = {0.f, 0.f, 0.f, 0.f};
#pragma unroll
            for (int ks = 0; ks < KT; ++ks) acc = mfma16(A[mt][ks], B[ks], acc);
#pragma unroll
            for (int i = 0; i < 4; ++i) {
                const f16 v = (f16)fmaxf(acc[i] + bv, 0.0f);
                const int row = 16*mt + 4*q0 + i;
                *(f16*)(O + row * RSOb + ((2*(16*nt + c0)) ^ ((row & 7) << 4))) = v;
            }
        }
    }
}

// ---- round-5 proven fused tile body (LDS-read-at-use phases, 136-VGPR shape),
//      with optional output indirection via sidx.
__device__ __forceinline__ void tile_body(
    const float* __restrict__ pts, const unsigned short* __restrict__ ws,
    const float* __restrict__ lin0_b, const float* __restrict__ lin1_b,
    const float* __restrict__ comb0_b, const float* __restrict__ comb1_b,
    const float* __restrict__ out_w, const float* __restrict__ out_b,
    const float* __restrict__ clin0_b, const float* __restrict__ clin1_b,
    const float* __restrict__ cout_w, const float* __restrict__ cout_b,
    float* __restrict__ out, char* L, int pbase, int lane, int c0, int q0,
    const int* __restrict__ sidx, int use_idx) {
    const unsigned short* WB  = ws + WBOFF;
    const unsigned short* W0  = WB;
    const unsigned short* W1  = WB + 2048;
    const unsigned short* WC0 = WB + 6144;
    const unsigned short* WC1 = WB + 18432;
    const unsigned short* WL0 = WB + 34816;
    const unsigned short* WL1 = WB + 36864;

    // coarse + fine gathers upfront (fine latency hides under lin0/lin1)
    gather3<3>(ws + PXY_C, ws + PXZ_C, ws + PYZ_C, 128, pts, pbase, lane, L);
    gather3<3>(ws + PXY_F, ws + PXZ_F, ws + PYZ_F, 512, pts, pbase, lane, L + 12288);
    LDS_FENCE();
    // lin0: K=32, FEATC@0 -> H0@4096
    {
        f16x8 A[4][1];
        ldA<1, 3>(A, L, 64, c0, q0);
        gemm_store<1, 4>(A, L + 4096, 128, W0, 32, lin0_b, c0, q0);
    }
    LDS_FENCE();
    // lin1: K=64, H0 -> H1@0 (A cached before stores)
    {
        f16x8 A[4][2];
        ldA<2, 7>(A, L + 4096, 128, c0, q0);
        LDS_FENCE();
        gemm_store<2, 4>(A, L, 128, W1, 64, lin1_b, c0, q0);
    }
    LDS_FENCE();
    // comb0: A=[H1 | FEATF@12288], K=96 -> H2@0 (rows 256B)
    {
        f16x8 A[4][3];
#pragma unroll
        for (int mt = 0; mt < 4; ++mt) {
            const int row = 16*mt + c0;
#pragma unroll
            for (int ks = 0; ks < 2; ++ks)
                A[mt][ks] = *(const f16x8*)(L + row * 128 + ((16*q0 + 64*ks) ^ ((row & 7) << 4)));
            A[mt][2] = *(const f16x8*)(L + 12288 + row * 64 + ((16*q0) ^ ((row & 3) << 4)));
        }
        LDS_FENCE();
        gemm_store<3, 8>(A, L, 256, WC0, 96, comb0_b, c0, q0);
    }
    LDS_FENCE();
    // comb1: K=128, A[4][4] cached; color gather overlapped under the MFMAs,
    // writing FEATC2@0 directly (A fully in regs; per-wave DS ordering + fence safe)
    float part[16];
#pragma unroll
    for (int r = 0; r < 16; ++r) part[r] = 0.f;
    {
        f16x8 A[4][4];
        ldA<4, 7>(A, L, 256, c0, q0);
        LDS_FENCE();
        gather3<3>(ws + PCXY, ws + PCXZ, ws + PCYZ, 256, pts, pbase, lane, L);
#pragma unroll
        for (int nt = 0; nt < 8; ++nt) {
            f16x8 B[4];
#pragma unroll
            for (int ks = 0; ks < 4; ++ks)
                B[ks] = *(const f16x8*)(WC1 + (size_t)(16*nt + c0) * 128 + 8*q0 + 32*ks);
            const float bv = comb1_b[16*nt + c0];
            const float wo = out_w[16*nt + c0];
#pragma unroll
            for (int mt = 0; mt < 4; ++mt) {
                f32x4 acc = {0.f, 0.f, 0.f, 0.f};
#pragma unroll
                for (int ks = 0; ks < 4; ++ks) acc = mfma16(A[mt][ks], B[ks], acc);
#pragma unroll
                for (int i = 0; i < 4; ++i)
                    part[4*mt + i] += wo * fmaxf(acc[i] + bv, 0.0f);
            }
        }
    }
    LDS_FENCE();
    // clin0: K=32, FEATC2@0 -> HC0@4096
    {
        f16x8 A[4][1];
        ldA<1, 3>(A, L, 64, c0, q0);
        gemm_store<1, 4>(A, L + 4096, 128, WL0, 32, clin0_b, c0, q0);
    }
    LDS_FENCE();
    // clin1: K=64, fused cout fold
    float pc0[16], pc1[16], pc2[16];
#pragma unroll
    for (int r = 0; r < 16; ++r) { pc0[r] = 0.f; pc1[r] = 0.f; pc2[r] = 0.f; }
    {
        f16x8 A[4][2];
        ldA<2, 7>(A, L + 4096, 128, c0, q0);
        LDS_FENCE();
#pragma unroll
        for (int nt = 0; nt < 4; ++nt) {
            f16x8 B[2];
#pragma unroll
            for (int ks = 0; ks < 2; ++ks)
                B[ks] = *(const f16x8*)(WL1 + (size_t)(16*nt + c0) * 64 + 8*q0 + 32*ks);
            const float bv  = clin1_b[16*nt + c0];
            const float cw0 = cout_w[16*nt + c0];
            const float cw1 = cout_w[64 + 16*nt + c0];
            const float cw2 = cout_w[128 + 16*nt + c0];
#pragma unroll
            for (int mt = 0; mt < 4; ++mt) {
                f32x4 acc = {0.f, 0.f, 0.f, 0.f};
#pragma unroll
                for (int ks = 0; ks < 2; ++ks) acc = mfma16(A[mt][ks], B[ks], acc);
#pragma unroll
                for (int i = 0; i < 4; ++i) {
                    const float hv = fmaxf(acc[i] + bv, 0.0f);
                    pc0[4*mt+i] += cw0 * hv;
                    pc1[4*mt+i] += cw1 * hv;
                    pc2[4*mt+i] += cw2 * hv;
                }
            }
        }
    }
    // epilogue: LDS transpose-reduce over the 16 c0 lanes, float4 store (indirected)
#pragma unroll
    for (int mt = 0; mt < 4; ++mt)
#pragma unroll
        for (int i = 0; i < 4; ++i) {
            const int r = 4*mt + i;
            const int row = 16*mt + 4*q0 + i;
            float4 v; v.x = pc0[r]; v.y = pc1[r]; v.z = pc2[r]; v.w = part[r];
            *(float4*)(L + row * 256 + ((c0 * 16) ^ ((row & 7) << 4))) = v;
        }
    LDS_FENCE();
    {
        float4 s; s.x = 0.f; s.y = 0.f; s.z = 0.f; s.w = 0.f;
#pragma unroll
        for (int c = 0; c < 16; ++c) {
            float4 v = *(const float4*)(L + lane * 256 + ((c * 16) ^ ((lane & 7) << 4)));
            s.x += v.x; s.y += v.y; s.z += v.z; s.w += v.w;
        }
        float4 o;
        o.x = 1.0f / (1.0f + __expf(-(s.x + cout_b[0])));
        o.y = 1.0f / (1.0f + __expf(-(s.y + cout_b[1])));
        o.z = 1.0f / (1.0f + __expf(-(s.z + cout_b[2])));
        o.w = s.w + out_b[0];
        const int orow = use_idx ? sidx[pbase + lane] : (pbase + lane);
        *(float4*)(out + 4 * (size_t)orow) = o;
    }
}

// ---- main kernel: sorted points, fused gather+MLP, XCD-chunked block order.
__global__ __launch_bounds__(128) void decoder_sorted(
    const float* __restrict__ sxyz, const unsigned short* __restrict__ ws,
    const float* __restrict__ lin0_b, const float* __restrict__ lin1_b,
    const float* __restrict__ comb0_b, const float* __restrict__ comb1_b,
    const float* __restrict__ out_w, const float* __restrict__ out_b,
    const float* __restrict__ clin0_b, const float* __restrict__ clin1_b,
    const float* __restrict__ cout_w, const float* __restrict__ cout_b,
    float* __restrict__ out, const int* __restrict__ sidx) {
    __shared__ __align__(16) unsigned short lds[2][8192];
    const int wave = threadIdx.x >> 6, lane = threadIdx.x & 63;
    const int c0 = lane & 15, q0 = lane >> 4;
    const int nblk = (N_TILES + 1) / 2;           // 7813
    const int q = nblk >> 3, r = nblk & 7;
    const int xcd = blockIdx.x & 7, j = blockIdx.x >> 3;
    const int sb = (xcd < r ? xcd * (q + 1) : r * (q + 1) + (xcd - r) * q) + j;
    const int tl = sb * 2 + wave;
    if (tl >= N_TILES) return;
    tile_body(sxyz, ws, lin0_b, lin1_b, comb0_b, comb1_b, out_w, out_b,
              clin0_b, clin1_b, cout_w, cout_b, out,
              (char*)lds[wave], tl * 64, lane, c0, q0, sidx, 1);
}

// ---- fallback (ws too small for sort region): fused on raw points, identity order.
__global__ __launch_bounds__(128) void decoder_main(
    const float* __restrict__ p, const unsigned short* __restrict__ ws,
    const float* __restrict__ lin0_b, const float* __restrict__ lin1_b,
    const float* __restrict__ comb0_b, const float* __restrict__ comb1_b,
    const float* __restrict__ out_w, const float* __restrict__ out_b,
    const float* __restrict__ clin0_b, const float* __restrict__ clin1_b,
    const float* __restrict__ cout_w, const float* __restrict__ cout_b,
    float* __restrict__ out) {
    __shared__ __align__(16) unsigned short lds[2][8192];
    const int wave = threadIdx.x >> 6, lane = threadIdx.x & 63;
    const int c0 = lane & 15, q0 = lane >> 4;
    const int tl = blockIdx.x * 2 + wave;
    if (tl >= N_TILES) return;
    tile_body(p, ws, lin0_b, lin1_b, comb0_b, comb1_b, out_w, out_b,
              clin0_b, clin1_b, cout_w, cout_b, out,
              (char*)lds[wave], tl * 64, lane, c0, q0, nullptr, 0);
}

extern "C" void kernel_launch(void* const* d_in, const int* in_sizes, int n_in,
                              void* d_out, int out_size, void* d_ws, size_t ws_size,
                              hipStream_t stream) {
    if (ws_size < FIXED_BYTES) return;
    unsigned short* ws = (unsigned short*)d_ws;
    char* wsb = (char*)d_ws;

    transpose_all<<<4032, 256, 0, stream>>>(
        (const float*)d_in[1], (const float*)d_in[2], (const float*)d_in[3],
        (const float*)d_in[4], (const float*)d_in[5], (const float*)d_in[6],
        (const float*)d_in[7], (const float*)d_in[8], (const float*)d_in[9], ws);
    weights_all<<<160, 256, 0, stream>>>(
        (const float*)d_in[10], (const float*)d_in[12], (const float*)d_in[14],
        (const float*)d_in[16], (const float*)d_in[20], (const float*)d_in[22],
        ws + WBOFF);

    const float* p = (const float*)d_in[0];
    const float* lin0_b  = (const float*)d_in[11];
    const float* lin1_b  = (const float*)d_in[13];
    const float* comb0_b = (const float*)d_in[15];
    const float* comb1_b = (const float*)d_in[17];
    const float* out_w   = (const float*)d_in[18];
    const float* out_b   = (const float*)d_in[19];
    const float* clin0_b = (const float*)d_in[21];
    const float* clin1_b = (const float*)d_in[23];
    const float* cout_w  = (const float*)d_in[24];
    const float* cout_b  = (const float*)d_in[25];
    float* out = (float*)d_out;

    if (ws_size >= SORT_END) {
        int*   hist   = (int*)(wsb + HIST_B);
        int*   cursor = (int*)(wsb + CURS_B);
        int*   sidx   = (int*)(wsb + SIDX_B);
        float* sxyz   = (float*)(wsb + SXYZ_B);

        hipMemsetAsync(hist, 0, NBKT * sizeof(int), stream);
        hist_kernel<<<(N_PTS + 255) / 256, 256, 0, stream>>>(p, hist);
        scan_kernel<<<1, 1024, 0, stream>>>(hist, cursor);
        scatter_kernel<<<(N_PTS + 255) / 256, 256, 0, stream>>>(p, cursor, sxyz, sidx);

        decoder_sorted<<<(N_TILES + 1) / 2, 128, 0, stream>>>(sxyz, ws,
            lin0_b, lin1_b, comb0_b, comb1_b, out_w, out_b,
            clin0_b, clin1_b, cout_w, cout_b, out, sidx);
    } else {
        decoder_main<<<(N_TILES + 1) / 2, 128, 0, stream>>>(p, ws,
            lin0_b, lin1_b, comb0_b, comb1_b, out_w, out_b,
            clin0_b, clin1_b, cout_w, cout_b, out);
    }
}

// Round 12
// 537.707 us; speedup vs baseline: 1.1470x; 1.1470x over previous
//
#include <hip/hip_runtime.h>

#define N_PTS   1000000
#define N_TILES 15625
#define NBKT    32768

typedef _Float16 f16;
typedef _Float16 f16x2 __attribute__((ext_vector_type(2)));
typedef _Float16 f16x8 __attribute__((ext_vector_type(8)));
typedef float    f32x4 __attribute__((ext_vector_type(4)));

// ws layout (f16 elements), planes channel-last [H][W][32]
#define PXY_C 0
#define PXZ_C 524288
#define PYZ_C 1048576
#define PXY_F 1572864
#define PXZ_F 9961472
#define PYZ_F 18350080
#define PCXY  26738688
#define PCXZ  28835840
#define PCYZ  30932992
#define WBOFF 33030144
#define FIXED_BYTES ((size_t)(WBOFF + 40960) * 2)   // 66,142,208
// sort region (byte offsets from ws base)
#define HIST_B  66142208u
#define CURS_B  (HIST_B + 131072u)
#define SIDX_B  (HIST_B + 262144u)
#define SXYZ_B  (SIDX_B + 4000000u)
#define SORT_END (SXYZ_B + 12000000u)               // 82,404,352

__device__ __forceinline__ f32x4 mfma16(f16x8 a, f16x8 b, f32x4 c) {
    return __builtin_amdgcn_mfma_f32_16x16x32_f16(a, b, c, 0, 0, 0);
}

#define LDS_FENCE() asm volatile("s_waitcnt lgkmcnt(0)" ::: "memory")

// ---- merged pre-pass: all 9 planes [32,H,W] f32 -> [H,W,32] f16  (r11-proven)
__global__ __launch_bounds__(256) void transpose_all(
    const float* __restrict__ s0, const float* __restrict__ s1, const float* __restrict__ s2,
    const float* __restrict__ s3, const float* __restrict__ s4, const float* __restrict__ s5,
    const float* __restrict__ s6, const float* __restrict__ s7, const float* __restrict__ s8,
    unsigned short* __restrict__ ws) {
    const int b = blockIdx.x;
    const float* src;
    int npix;
    size_t doff;
    int pix0;
    if (b < 192) {                       // coarse: 3 x 64 blocks
        const int pl = b >> 6;
        src = pl == 0 ? s0 : (pl == 1 ? s1 : s2);
        npix = 16384; doff = (size_t)pl * 524288; pix0 = (b & 63) * 256;
    } else if (b < 3264) {               // fine: 3 x 1024 blocks
        const int t = b - 192, pl = t >> 10;
        src = pl == 0 ? s3 : (pl == 1 ? s4 : s5);
        npix = 262144; doff = 1572864 + (size_t)pl * 8388608; pix0 = (t & 1023) * 256;
    } else {                             // color: 3 x 256 blocks
        const int t = b - 3264, pl = t >> 8;
        src = pl == 0 ? s6 : (pl == 1 ? s7 : s8);
        npix = 65536; doff = 26738688 + (size_t)pl * 2097152; pix0 = (t & 255) * 256;
    }
    const int pix = pix0 + threadIdx.x;
    unsigned w[16];
#pragma unroll
    for (int j = 0; j < 16; ++j) {
        f16x2 v = { (f16)src[(size_t)(2*j) * npix + pix], (f16)src[(size_t)(2*j+1) * npix + pix] };
        w[j] = __builtin_bit_cast(unsigned, v);
    }
    unsigned short* dst = ws + doff + (size_t)pix * 32;
#pragma unroll
    for (int j = 0; j < 4; ++j) {
        uint4 o; o.x = w[4*j+0]; o.y = w[4*j+1]; o.z = w[4*j+2]; o.w = w[4*j+3];
        *(uint4*)(dst + 8*j) = o;
    }
}

// ---- merged pre-pass: all 6 weight matrices f32 -> f16 (r11-proven)
__global__ __launch_bounds__(256) void weights_all(
    const float* __restrict__ w0, const float* __restrict__ w1, const float* __restrict__ w2,
    const float* __restrict__ w3, const float* __restrict__ w4, const float* __restrict__ w5,
    unsigned short* __restrict__ dst) {
    const int u = blockIdx.x * 256 + threadIdx.x;   // [0, 40960)
    const float* src;
    int local;
    if (u < 2048)       { src = w0; local = u; }
    else if (u < 6144)  { src = w1; local = u - 2048; }
    else if (u < 18432) { src = w2; local = u - 6144; }
    else if (u < 34816) { src = w3; local = u - 18432; }
    else if (u < 36864) { src = w4; local = u - 34816; }
    else                { src = w5; local = u - 36864; }
    f16 h = (f16)src[local];
    dst[u] = __builtin_bit_cast(unsigned short, h);
}

// ---- Morton key (5 bits/axis, 32^3 cells)
__device__ __forceinline__ unsigned mpart5(unsigned v) {
    v &= 31u;
    v = (v | (v << 8)) & 0x100Fu;
    v = (v | (v << 4)) & 0x10C3u;
    v = (v | (v << 2)) & 0x1249u;
    return v;
}
__device__ __forceinline__ int morton_key(float x, float y, float z) {
    int gx = min(max((int)((x + 1.0f) * 16.0f), 0), 31);
    int gy = min(max((int)((y + 1.0f) * 16.0f), 0), 31);
    int gz = min(max((int)((z + 1.0f) * 16.0f), 0), 31);
    return (int)(mpart5((unsigned)gx) | (mpart5((unsigned)gy) << 1) | (mpart5((unsigned)gz) << 2));
}

__global__ __launch_bounds__(256) void hist_kernel(const float* __restrict__ p, int* __restrict__ hist) {
    int i = blockIdx.x * 256 + threadIdx.x;
    if (i >= N_PTS) return;
    atomicAdd(&hist[morton_key(p[3*(size_t)i], p[3*(size_t)i+1], p[3*(size_t)i+2])], 1);
}

__global__ __launch_bounds__(1024) void scan_kernel(const int* __restrict__ hist, int* __restrict__ cursor) {
    __shared__ int psum[1024];
    const int t = threadIdx.x;
    int s = 0;
    for (int j = 0; j < 32; ++j) s += hist[t * 32 + j];
    psum[t] = s;
    __syncthreads();
    for (int off = 1; off < 1024; off <<= 1) {
        int v = (t >= off) ? psum[t - off] : 0;
        __syncthreads();
        psum[t] += v;
        __syncthreads();
    }
    int run = (t > 0) ? psum[t - 1] : 0;
    for (int j = 0; j < 32; ++j) {
        const int idx = t * 32 + j;
        cursor[idx] = run;
        run += hist[idx];
    }
}

__global__ __launch_bounds__(256) void scatter_kernel(const float* __restrict__ p, int* __restrict__ cursor,
                                                      float* __restrict__ sxyz, int* __restrict__ sidx) {
    int i = blockIdx.x * 256 + threadIdx.x;
    if (i >= N_PTS) return;
    const float x = p[3*(size_t)i], y = p[3*(size_t)i+1], z = p[3*(size_t)i+2];
    const int pos = atomicAdd(&cursor[morton_key(x, y, z)], 1);
    sxyz[3*(size_t)pos]   = x;
    sxyz[3*(size_t)pos+1] = y;
    sxyz[3*(size_t)pos+2] = z;
    sidx[pos] = i;
}

// ---- coalesced 3-plane bilinear gather, one 64-pt tile (proven math).
template <int SW>
__device__ __forceinline__ void gather3(
    const unsigned short* __restrict__ P0, const unsigned short* __restrict__ P1,
    const unsigned short* __restrict__ P2, int R,
    const float* __restrict__ p, int ptbase, int lane, char* dst) {
    const int sub = lane >> 2, ch = lane & 3;
    const float Rs = 0.5f * (float)(R - 1);
#pragma unroll
    for (int r = 0; r < 4; ++r) {
        const int row = r * 16 + sub;
        const float* pp = p + 3 * (size_t)(ptbase + row);
        const float pa = pp[0], pb = pp[1], pc = pp[2];
        f16x2 a0 = {0,0}, a1 = {0,0}, a2 = {0,0}, a3 = {0,0};
        const float cA[3] = {pa, pa, pb};
        const float cB[3] = {pb, pc, pc};
        const unsigned short* tp[3] = {P0, P1, P2};
#pragma unroll
        for (int pl = 0; pl < 3; ++pl) {
            float x = (cA[pl] + 1.0f) * Rs;
            float y = (cB[pl] + 1.0f) * Rs;
            float fx = floorf(x), fy = floorf(y);
            float wx = x - fx, wy = y - fy;
            int x0 = min(max((int)fx, 0), R - 1);
            int x1 = min(x0 + 1, R - 1);
            int y0 = min(max((int)fy, 0), R - 1);
            int y1 = min(y0 + 1, R - 1);
            const unsigned short* b = tp[pl];
            uint4 v00 = *(const uint4*)(b + (size_t)(y0 * R + x0) * 32 + ch * 8);
            uint4 v01 = *(const uint4*)(b + (size_t)(y0 * R + x1) * 32 + ch * 8);
            uint4 v10 = *(const uint4*)(b + (size_t)(y1 * R + x0) * 32 + ch * 8);
            uint4 v11 = *(const uint4*)(b + (size_t)(y1 * R + x1) * 32 + ch * 8);
            f16 h00 = (f16)((1.0f - wx) * (1.0f - wy));
            f16 h01 = (f16)(wx * (1.0f - wy));
            f16 h10 = (f16)((1.0f - wx) * wy);
            f16 h11 = (f16)(wx * wy);
            f16x2 w00 = {h00, h00}, w01 = {h01, h01}, w10 = {h10, h10}, w11 = {h11, h11};
            a0 += __builtin_bit_cast(f16x2, v00.x) * w00 + __builtin_bit_cast(f16x2, v01.x) * w01
                + __builtin_bit_cast(f16x2, v10.x) * w10 + __builtin_bit_cast(f16x2, v11.x) * w11;
            a1 += __builtin_bit_cast(f16x2, v00.y) * w00 + __builtin_bit_cast(f16x2, v01.y) * w01
                + __builtin_bit_cast(f16x2, v10.y) * w10 + __builtin_bit_cast(f16x2, v11.y) * w11;
            a2 += __builtin_bit_cast(f16x2, v00.z) * w00 + __builtin_bit_cast(f16x2, v01.z) * w01
                + __builtin_bit_cast(f16x2, v10.z) * w10 + __builtin_bit_cast(f16x2, v11.z) * w11;
            a3 += __builtin_bit_cast(f16x2, v00.w) * w00 + __builtin_bit_cast(f16x2, v01.w) * w01
                + __builtin_bit_cast(f16x2, v10.w) * w10 + __builtin_bit_cast(f16x2, v11.w) * w11;
        }
        uint4 o;
        o.x = __builtin_bit_cast(unsigned, a0);
        o.y = __builtin_bit_cast(unsigned, a1);
        o.z = __builtin_bit_cast(unsigned, a2);
        o.w = __builtin_bit_cast(unsigned, a3);
        *(uint4*)(dst + row * 64 + ((ch * 16) ^ ((row & SW) << 4))) = o;
    }
}

// A-frag loads from swizzled LDS
template <int KT, int SWA>
__device__ __forceinline__ void ldA(f16x8 (&A)[4][KT], const char* src, int RSb, int c0, int q0) {
#pragma unroll
    for (int mt = 0; mt < 4; ++mt) {
        const int row = 16 * mt + c0;
#pragma unroll
        for (int ks = 0; ks < KT; ++ks)
            A[mt][ks] = *(const f16x8*)(src + row * RSb + ((16*q0 + 64*ks) ^ ((row & SWA) << 4)));
    }
}

// GEMM: A (regs) x W[N][K] (global f16) -> relu -> LDS, swizzle (row&7)<<4
template <int KT, int NT>
__device__ __forceinline__ void gemm_store(const f16x8 (&A)[4][KT], char* O, int RSOb,
                                           const unsigned short* __restrict__ Wg, int K,
                                           const float* __restrict__ bias, int c0, int q0) {
#pragma unroll
    for (int nt = 0; nt < NT; ++nt) {
        f16x8 B[KT];
#pragma unroll
        for (int ks = 0; ks < KT; ++ks)
            B[ks] = *(const f16x8*)(Wg + (size_t)(16*nt + c0) * K + 8*q0 + 32*ks);
        const float bv = bias[16*nt + c0];
#pragma unroll
        for (int mt = 0; mt < 4; ++mt) {
            f32x4 acc = {0.f, 0.f, 0.f, 0.f};
#pragma unroll
            for (int ks = 0; ks < KT; ++ks) acc = mfma16(A[mt][ks], B[ks], acc);
#pragma unroll
            for (int i = 0; i < 4; ++i) {
                const f16 v = (f16)fmaxf(acc[i] + bv, 0.0f);
                const int row = 16*mt + 4*q0 + i;
                *(f16*)(O + row * RSOb + ((2*(16*nt + c0)) ^ ((row & 7) << 4))) = v;
            }
        }
    }
}

// ---- MLP body (round-10 proven: fragments held in regs; output indirected via sidx)
__device__ __forceinline__ void mlp_body(
    char* L, const unsigned short* WB,
    const float* __restrict__ lin0_b, const float* __restrict__ lin1_b,
    const float* __restrict__ comb0_b, const float* __restrict__ comb1_b,
    const float* __restrict__ out_w, const float* __restrict__ out_b,
    const float* __restrict__ clin0_b, const float* __restrict__ clin1_b,
    const float* __restrict__ cout_w, const float* __restrict__ cout_b,
    const f16x8 (&A0)[4][1], const f16x8 (&AF)[4], const f16x8 (&AC)[4][1],
    int c0, int q0, int lane, float* __restrict__ out, int ptbase,
    const int* __restrict__ sidx, int use_idx) {
    const unsigned short* W0  = WB;
    const unsigned short* W1  = WB + 2048;
    const unsigned short* WC0 = WB + 6144;
    const unsigned short* WC1 = WB + 18432;
    const unsigned short* WL0 = WB + 34816;
    const unsigned short* WL1 = WB + 36864;

    gemm_store<1, 4>(A0, L + 4096, 128, W0, 32, lin0_b, c0, q0);
    LDS_FENCE();
    {
        f16x8 A[4][2];
        ldA<2, 7>(A, L + 4096, 128, c0, q0);
        LDS_FENCE();
        gemm_store<2, 4>(A, L, 128, W1, 64, lin1_b, c0, q0);
    }
    LDS_FENCE();
    {
        f16x8 A[4][3];
#pragma unroll
        for (int mt = 0; mt < 4; ++mt) {
            const int row = 16*mt + c0;
#pragma unroll
            for (int ks = 0; ks < 2; ++ks)
                A[mt][ks] = *(const f16x8*)(L + row * 128 + ((16*q0 + 64*ks) ^ ((row & 7) << 4)));
            A[mt][2] = AF[mt];
        }
        LDS_FENCE();
        gemm_store<3, 8>(A, L, 256, WC0, 96, comb0_b, c0, q0);
    }
    LDS_FENCE();
    float part[16];
#pragma unroll
    for (int r = 0; r < 16; ++r) part[r] = 0.f;
    {
        f16x8 A[4][4];
        ldA<4, 7>(A, L, 256, c0, q0);
        LDS_FENCE();
#pragma unroll
        for (int nt = 0; nt < 8; ++nt) {
            f16x8 B[4];
#pragma unroll
            for (int ks = 0; ks < 4; ++ks)
                B[ks] = *(const f16x8*)(WC1 + (size_t)(16*nt + c0) * 128 + 8*q0 + 32*ks);
            const float bv = comb1_b[16*nt + c0];
            const float wo = out_w[16*nt + c0];
#pragma unroll
            for (int mt = 0; mt < 4; ++mt) {
                f32x4 acc = {0.f, 0.f, 0.f, 0.f};
#pragma unroll
                for (int ks = 0; ks < 4; ++ks) acc = mfma16(A[mt][ks], B[ks], acc);
#pragma unroll
                for (int i = 0; i < 4; ++i)
                    part[4*mt + i] += wo * fmaxf(acc[i] + bv, 0.0f);
            }
        }
    }
    LDS_FENCE();
    gemm_store<1, 4>(AC, L + 4096, 128, WL0, 32, clin0_b, c0, q0);
    LDS_FENCE();
    float pc0[16], pc1[16], pc2[16];
#pragma unroll
    for (int r = 0; r < 16; ++r) { pc0[r] = 0.f; pc1[r] = 0.f; pc2[r] = 0.f; }
    {
        f16x8 A[4][2];
        ldA<2, 7>(A, L + 4096, 128, c0, q0);
        LDS_FENCE();
#pragma unroll
        for (int nt = 0; nt < 4; ++nt) {
            f16x8 B[2];
#pragma unroll
            for (int ks = 0; ks < 2; ++ks)
                B[ks] = *(const f16x8*)(WL1 + (size_t)(16*nt + c0) * 64 + 8*q0 + 32*ks);
            const float bv  = clin1_b[16*nt + c0];
            const float cw0 = cout_w[16*nt + c0];
            const float cw1 = cout_w[64 + 16*nt + c0];
            const float cw2 = cout_w[128 + 16*nt + c0];
#pragma unroll
            for (int mt = 0; mt < 4; ++mt) {
                f32x4 acc = {0.f, 0.f, 0.f, 0.f};
#pragma unroll
                for (int ks = 0; ks < 2; ++ks) acc = mfma16(A[mt][ks], B[ks], acc);
#pragma unroll
                for (int i = 0; i < 4; ++i) {
                    const float hv = fmaxf(acc[i] + bv, 0.0f);
                    pc0[4*mt+i] += cw0 * hv;
                    pc1[4*mt+i] += cw1 * hv;
                    pc2[4*mt+i] += cw2 * hv;
                }
            }
        }
    }
#pragma unroll
    for (int mt = 0; mt < 4; ++mt)
#pragma unroll
        for (int i = 0; i < 4; ++i) {
            const int r = 4*mt + i;
            const int row = 16*mt + 4*q0 + i;
            float4 v; v.x = pc0[r]; v.y = pc1[r]; v.z = pc2[r]; v.w = part[r];
            *(float4*)(L + row * 256 + ((c0 * 16) ^ ((row & 7) << 4))) = v;
        }
    LDS_FENCE();
    {
        float4 s; s.x = 0.f; s.y = 0.f; s.z = 0.f; s.w = 0.f;
#pragma unroll
        for (int c = 0; c < 16; ++c) {
            float4 v = *(const float4*)(L + lane * 256 + ((c * 16) ^ ((lane & 7) << 4)));
            s.x += v.x; s.y += v.y; s.z += v.z; s.w += v.w;
        }
        float4 o;
        o.x = 1.0f / (1.0f + __expf(-(s.x + cout_b[0])));
        o.y = 1.0f / (1.0f + __expf(-(s.y + cout_b[1])));
        o.z = 1.0f / (1.0f + __expf(-(s.z + cout_b[2])));
        o.w = s.w + out_b[0];
        const int orow = use_idx ? sidx[ptbase + lane] : (ptbase + lane);
        *(float4*)(out + 4 * (size_t)orow) = o;
    }
}

// ---- fused tile body (round-10 proven: 3 gathers upfront, fragments held)
__device__ __forceinline__ void fused_tile(
    const float* __restrict__ pts, const unsigned short* __restrict__ ws,
    const float* lin0_b, const float* lin1_b, const float* comb0_b, const float* comb1_b,
    const float* out_w, const float* out_b, const float* clin0_b, const float* clin1_b,
    const float* cout_w, const float* cout_b, float* out,
    char* L, int pbase, int lane, int c0, int q0,
    const int* __restrict__ sidx, int use_idx) {
    const unsigned short* WB = ws + WBOFF;
    gather3<3>(ws + PXY_C, ws + PXZ_C, ws + PYZ_C, 128, pts, pbase, lane, L);
    gather3<3>(ws + PXY_F, ws + PXZ_F, ws + PYZ_F, 512, pts, pbase, lane, L + 12288);
    LDS_FENCE();
    f16x8 A0[4][1], AC[4][1], AF[4];
#pragma unroll
    for (int mt = 0; mt < 4; ++mt) {
        const int row = 16*mt + c0;
        A0[mt][0] = *(const f16x8*)(L + row * 64 + ((16*q0) ^ ((row & 3) << 4)));
        AF[mt]    = *(const f16x8*)(L + 12288 + row * 64 + ((16*q0) ^ ((row & 3) << 4)));
    }
    LDS_FENCE();
    gather3<3>(ws + PCXY, ws + PCXZ, ws + PCYZ, 256, pts, pbase, lane, L + 12288);
    LDS_FENCE();
#pragma unroll
    for (int mt = 0; mt < 4; ++mt) {
        const int row = 16*mt + c0;
        AC[mt][0] = *(const f16x8*)(L + 12288 + row * 64 + ((16*q0) ^ ((row & 3) << 4)));
    }
    LDS_FENCE();
    mlp_body(L, WB, lin0_b, lin1_b, comb0_b, comb1_b, out_w, out_b,
             clin0_b, clin1_b, cout_w, cout_b, A0, AF, AC, c0, q0, lane,
             out, pbase, sidx, use_idx);
}

// ---- main kernel: sorted points, fused gather+MLP, XCD-chunked block order.
__global__ __launch_bounds__(128) void decoder_sorted(
    const float* __restrict__ sxyz, const unsigned short* __restrict__ ws,
    const float* __restrict__ lin0_b, const float* __restrict__ lin1_b,
    const float* __restrict__ comb0_b, const float* __restrict__ comb1_b,
    const float* __restrict__ out_w, const float* __restrict__ out_b,
    const float* __restrict__ clin0_b, const float* __restrict__ clin1_b,
    const float* __restrict__ cout_w, const float* __restrict__ cout_b,
    float* __restrict__ out, const int* __restrict__ sidx) {
    __shared__ __align__(16) unsigned short lds[2][8192];
    const int wave = threadIdx.x >> 6, lane = threadIdx.x & 63;
    const int c0 = lane & 15, q0 = lane >> 4;
    const int nblk = (N_TILES + 1) / 2;           // 7813
    const int q = nblk >> 3, r = nblk & 7;
    const int xcd = blockIdx.x & 7, j = blockIdx.x >> 3;
    const int sb = (xcd < r ? xcd * (q + 1) : r * (q + 1) + (xcd - r) * q) + j;
    const int tl = sb * 2 + wave;
    if (tl >= N_TILES) return;
    fused_tile(sxyz, ws, lin0_b, lin1_b, comb0_b, comb1_b, out_w, out_b,
               clin0_b, clin1_b, cout_w, cout_b, out,
               (char*)lds[wave], tl * 64, lane, c0, q0, sidx, 1);
}

// ---- fallback (ws too small for sort region): fused on raw points, identity order.
__global__ __launch_bounds__(128) void decoder_main(
    const float* __restrict__ p, const unsigned short* __restrict__ ws,
    const float* __restrict__ lin0_b, const float* __restrict__ lin1_b,
    const float* __restrict__ comb0_b, const float* __restrict__ comb1_b,
    const float* __restrict__ out_w, const float* __restrict__ out_b,
    const float* __restrict__ clin0_b, const float* __restrict__ clin1_b,
    const float* __restrict__ cout_w, const float* __restrict__ cout_b,
    float* __restrict__ out) {
    __shared__ __align__(16) unsigned short lds[2][8192];
    const int wave = threadIdx.x >> 6, lane = threadIdx.x & 63;
    const int c0 = lane & 15, q0 = lane >> 4;
    const int tl = blockIdx.x * 2 + wave;
    if (tl >= N_TILES) return;
    fused_tile(p, ws, lin0_b, lin1_b, comb0_b, comb1_b, out_w, out_b,
               clin0_b, clin1_b, cout_w, cout_b, out,
               (char*)lds[wave], tl * 64, lane, c0, q0, nullptr, 0);
}

extern "C" void kernel_launch(void* const* d_in, const int* in_sizes, int n_in,
                              void* d_out, int out_size, void* d_ws, size_t ws_size,
                              hipStream_t stream) {
    if (ws_size < FIXED_BYTES) return;
    unsigned short* ws = (unsigned short*)d_ws;
    char* wsb = (char*)d_ws;

    transpose_all<<<4032, 256, 0, stream>>>(
        (const float*)d_in[1], (const float*)d_in[2], (const float*)d_in[3],
        (const float*)d_in[4], (const float*)d_in[5], (const float*)d_in[6],
        (const float*)d_in[7], (const float*)d_in[8], (const float*)d_in[9], ws);
    weights_all<<<160, 256, 0, stream>>>(
        (const float*)d_in[10], (const float*)d_in[12], (const float*)d_in[14],
        (const float*)d_in[16], (const float*)d_in[20], (const float*)d_in[22],
        ws + WBOFF);

    const float* p = (const float*)d_in[0];
    const float* lin0_b  = (const float*)d_in[11];
    const float* lin1_b  = (const float*)d_in[13];
    const float* comb0_b = (const float*)d_in[15];
    const float* comb1_b = (const float*)d_in[17];
    const float* out_w   = (const float*)d_in[18];
    const float* out_b   = (const float*)d_in[19];
    const float* clin0_b = (const float*)d_in[21];
    const float* clin1_b = (const float*)d_in[23];
    const float* cout_w  = (const float*)d_in[24];
    const float* cout_b  = (const float*)d_in[25];
    float* out = (float*)d_out;

    if (ws_size >= SORT_END) {
        int*   hist   = (int*)(wsb + HIST_B);
        int*   cursor = (int*)(wsb + CURS_B);
        int*   sidx   = (int*)(wsb + SIDX_B);
        float* sxyz   = (float*)(wsb + SXYZ_B);

        hipMemsetAsync(hist, 0, NBKT * sizeof(int), stream);
        hist_kernel<<<(N_PTS + 255) / 256, 256, 0, stream>>>(p, hist);
        scan_kernel<<<1, 1024, 0, stream>>>(hist, cursor);
        scatter_kernel<<<(N_PTS + 255) / 256, 256, 0, stream>>>(p, cursor, sxyz, sidx);

        decoder_sorted<<<(N_TILES + 1) / 2, 128, 0, stream>>>(sxyz, ws,
            lin0_b, lin1_b, comb0_b, comb1_b, out_w, out_b,
            clin0_b, clin1_b, cout_w, cout_b, out, sidx);
    } else {
        decoder_main<<<(N_TILES + 1) / 2, 128, 0, stream>>>(p, ws,
            lin0_b, lin1_b, comb0_b, comb1_b, out_w, out_b,
            clin0_b, clin1_b, cout_w, cout_b, out);
    }
}

// Round 13
// 486.678 us; speedup vs baseline: 1.2672x; 1.1049x over previous
//
#include <hip/hip_runtime.h>

#define N_PTS   1000000
#define N_TILES 15625
#define NBKT    32768

typedef _Float16 f16;
typedef _Float16 f16x2 __attribute__((ext_vector_type(2)));
typedef _Float16 f16x8 __attribute__((ext_vector_type(8)));
typedef float    f32x4 __attribute__((ext_vector_type(4)));

// ws layout (f16 elements), planes channel-last [H][W][32]
#define PXY_C 0
#define PXZ_C 524288
#define PYZ_C 1048576
#define PXY_F 1572864
#define PXZ_F 9961472
#define PYZ_F 18350080
#define PCXY  26738688
#define PCXZ  28835840
#define PCYZ  30932992
#define WBOFF 33030144
#define FIXED_BYTES ((size_t)(WBOFF + 40960) * 2)   // 66,142,208
// sort region (byte offsets from ws base)
#define HIST_B  66142208u
#define CURS_B  (HIST_B + 131072u)
#define SIDX_B  (HIST_B + 262144u)
#define SXYZ_B  (SIDX_B + 4000000u)
#define SORT_END (SXYZ_B + 12000000u)               // 82,404,352

__device__ __forceinline__ f32x4 mfma16(f16x8 a, f16x8 b, f32x4 c) {
    return __builtin_amdgcn_mfma_f32_16x16x32_f16(a, b, c, 0, 0, 0);
}

#define LDS_FENCE() asm volatile("s_waitcnt lgkmcnt(0)" ::: "memory")

// ---- merged pre-pass: all 9 planes [32,H,W] f32 -> [H,W,32] f16  (r11-proven)
__global__ __launch_bounds__(256) void transpose_all(
    const float* __restrict__ s0, const float* __restrict__ s1, const float* __restrict__ s2,
    const float* __restrict__ s3, const float* __restrict__ s4, const float* __restrict__ s5,
    const float* __restrict__ s6, const float* __restrict__ s7, const float* __restrict__ s8,
    unsigned short* __restrict__ ws) {
    const int b = blockIdx.x;
    const float* src;
    int npix;
    size_t doff;
    int pix0;
    if (b < 192) {                       // coarse: 3 x 64 blocks
        const int pl = b >> 6;
        src = pl == 0 ? s0 : (pl == 1 ? s1 : s2);
        npix = 16384; doff = (size_t)pl * 524288; pix0 = (b & 63) * 256;
    } else if (b < 3264) {               // fine: 3 x 1024 blocks
        const int t = b - 192, pl = t >> 10;
        src = pl == 0 ? s3 : (pl == 1 ? s4 : s5);
        npix = 262144; doff = 1572864 + (size_t)pl * 8388608; pix0 = (t & 1023) * 256;
    } else {                             // color: 3 x 256 blocks
        const int t = b - 3264, pl = t >> 8;
        src = pl == 0 ? s6 : (pl == 1 ? s7 : s8);
        npix = 65536; doff = 26738688 + (size_t)pl * 2097152; pix0 = (t & 255) * 256;
    }
    const int pix = pix0 + threadIdx.x;
    unsigned w[16];
#pragma unroll
    for (int j = 0; j < 16; ++j) {
        f16x2 v = { (f16)src[(size_t)(2*j) * npix + pix], (f16)src[(size_t)(2*j+1) * npix + pix] };
        w[j] = __builtin_bit_cast(unsigned, v);
    }
    unsigned short* dst = ws + doff + (size_t)pix * 32;
#pragma unroll
    for (int j = 0; j < 4; ++j) {
        uint4 o; o.x = w[4*j+0]; o.y = w[4*j+1]; o.z = w[4*j+2]; o.w = w[4*j+3];
        *(uint4*)(dst + 8*j) = o;
    }
}

// ---- merged pre-pass: all 6 weight matrices f32 -> f16 (r11-proven)
__global__ __launch_bounds__(256) void weights_all(
    const float* __restrict__ w0, const float* __restrict__ w1, const float* __restrict__ w2,
    const float* __restrict__ w3, const float* __restrict__ w4, const float* __restrict__ w5,
    unsigned short* __restrict__ dst) {
    const int u = blockIdx.x * 256 + threadIdx.x;   // [0, 40960)
    const float* src;
    int local;
    if (u < 2048)       { src = w0; local = u; }
    else if (u < 6144)  { src = w1; local = u - 2048; }
    else if (u < 18432) { src = w2; local = u - 6144; }
    else if (u < 34816) { src = w3; local = u - 18432; }
    else if (u < 36864) { src = w4; local = u - 34816; }
    else                { src = w5; local = u - 36864; }
    f16 h = (f16)src[local];
    dst[u] = __builtin_bit_cast(unsigned short, h);
}

// ---- Morton key (5 bits/axis, 32^3 cells)
__device__ __forceinline__ unsigned mpart5(unsigned v) {
    v &= 31u;
    v = (v | (v << 8)) & 0x100Fu;
    v = (v | (v << 4)) & 0x10C3u;
    v = (v | (v << 2)) & 0x1249u;
    return v;
}
__device__ __forceinline__ int morton_key(float x, float y, float z) {
    int gx = min(max((int)((x + 1.0f) * 16.0f), 0), 31);
    int gy = min(max((int)((y + 1.0f) * 16.0f), 0), 31);
    int gz = min(max((int)((z + 1.0f) * 16.0f), 0), 31);
    return (int)(mpart5((unsigned)gx) | (mpart5((unsigned)gy) << 1) | (mpart5((unsigned)gz) << 2));
}

__global__ __launch_bounds__(256) void hist_kernel(const float* __restrict__ p, int* __restrict__ hist) {
    int i = blockIdx.x * 256 + threadIdx.x;
    if (i >= N_PTS) return;
    atomicAdd(&hist[morton_key(p[3*(size_t)i], p[3*(size_t)i+1], p[3*(size_t)i+2])], 1);
}

__global__ __launch_bounds__(1024) void scan_kernel(const int* __restrict__ hist, int* __restrict__ cursor) {
    __shared__ int psum[1024];
    const int t = threadIdx.x;
    int s = 0;
    for (int j = 0; j < 32; ++j) s += hist[t * 32 + j];
    psum[t] = s;
    __syncthreads();
    for (int off = 1; off < 1024; off <<= 1) {
        int v = (t >= off) ? psum[t - off] : 0;
        __syncthreads();
        psum[t] += v;
        __syncthreads();
    }
    int run = (t > 0) ? psum[t - 1] : 0;
    for (int j = 0; j < 32; ++j) {
        const int idx = t * 32 + j;
        cursor[idx] = run;
        run += hist[idx];
    }
}

__global__ __launch_bounds__(256) void scatter_kernel(const float* __restrict__ p, int* __restrict__ cursor,
                                                      float* __restrict__ sxyz, int* __restrict__ sidx) {
    int i = blockIdx.x * 256 + threadIdx.x;
    if (i >= N_PTS) return;
    const float x = p[3*(size_t)i], y = p[3*(size_t)i+1], z = p[3*(size_t)i+2];
    const int pos = atomicAdd(&cursor[morton_key(x, y, z)], 1);
    sxyz[3*(size_t)pos]   = x;
    sxyz[3*(size_t)pos+1] = y;
    sxyz[3*(size_t)pos+2] = z;
    sidx[pos] = i;
}

// ---- coalesced 3-plane bilinear gather, one 64-pt tile (proven math).
template <int SW>
__device__ __forceinline__ void gather3(
    const unsigned short* __restrict__ P0, const unsigned short* __restrict__ P1,
    const unsigned short* __restrict__ P2, int R,
    const float* __restrict__ p, int ptbase, int lane, char* dst) {
    const int sub = lane >> 2, ch = lane & 3;
    const float Rs = 0.5f * (float)(R - 1);
#pragma unroll
    for (int r = 0; r < 4; ++r) {
        const int row = r * 16 + sub;
        const float* pp = p + 3 * (size_t)(ptbase + row);
        const float pa = pp[0], pb = pp[1], pc = pp[2];
        f16x2 a0 = {0,0}, a1 = {0,0}, a2 = {0,0}, a3 = {0,0};
        const float cA[3] = {pa, pa, pb};
        const float cB[3] = {pb, pc, pc};
        const unsigned short* tp[3] = {P0, P1, P2};
#pragma unroll
        for (int pl = 0; pl < 3; ++pl) {
            float x = (cA[pl] + 1.0f) * Rs;
            float y = (cB[pl] + 1.0f) * Rs;
            float fx = floorf(x), fy = floorf(y);
            float wx = x - fx, wy = y - fy;
            int x0 = min(max((int)fx, 0), R - 1);
            int x1 = min(x0 + 1, R - 1);
            int y0 = min(max((int)fy, 0), R - 1);
            int y1 = min(y0 + 1, R - 1);
            const unsigned short* b = tp[pl];
            uint4 v00 = *(const uint4*)(b + (size_t)(y0 * R + x0) * 32 + ch * 8);
            uint4 v01 = *(const uint4*)(b + (size_t)(y0 * R + x1) * 32 + ch * 8);
            uint4 v10 = *(const uint4*)(b + (size_t)(y1 * R + x0) * 32 + ch * 8);
            uint4 v11 = *(const uint4*)(b + (size_t)(y1 * R + x1) * 32 + ch * 8);
            f16 h00 = (f16)((1.0f - wx) * (1.0f - wy));
            f16 h01 = (f16)(wx * (1.0f - wy));
            f16 h10 = (f16)((1.0f - wx) * wy);
            f16 h11 = (f16)(wx * wy);
            f16x2 w00 = {h00, h00}, w01 = {h01, h01}, w10 = {h10, h10}, w11 = {h11, h11};
            a0 += __builtin_bit_cast(f16x2, v00.x) * w00 + __builtin_bit_cast(f16x2, v01.x) * w01
                + __builtin_bit_cast(f16x2, v10.x) * w10 + __builtin_bit_cast(f16x2, v11.x) * w11;
            a1 += __builtin_bit_cast(f16x2, v00.y) * w00 + __builtin_bit_cast(f16x2, v01.y) * w01
                + __builtin_bit_cast(f16x2, v10.y) * w10 + __builtin_bit_cast(f16x2, v11.y) * w11;
            a2 += __builtin_bit_cast(f16x2, v00.z) * w00 + __builtin_bit_cast(f16x2, v01.z) * w01
                + __builtin_bit_cast(f16x2, v10.z) * w10 + __builtin_bit_cast(f16x2, v11.z) * w11;
            a3 += __builtin_bit_cast(f16x2, v00.w) * w00 + __builtin_bit_cast(f16x2, v01.w) * w01
                + __builtin_bit_cast(f16x2, v10.w) * w10 + __builtin_bit_cast(f16x2, v11.w) * w11;
        }
        uint4 o;
        o.x = __builtin_bit_cast(unsigned, a0);
        o.y = __builtin_bit_cast(unsigned, a1);
        o.z = __builtin_bit_cast(unsigned, a2);
        o.w = __builtin_bit_cast(unsigned, a3);
        *(uint4*)(dst + row * 64 + ((ch * 16) ^ ((row & SW) << 4))) = o;
    }
}

// A-frag loads from swizzled LDS
template <int KT, int SWA>
__device__ __forceinline__ void ldA(f16x8 (&A)[4][KT], const char* src, int RSb, int c0, int q0) {
#pragma unroll
    for (int mt = 0; mt < 4; ++mt) {
        const int row = 16 * mt + c0;
#pragma unroll
        for (int ks = 0; ks < KT; ++ks)
            A[mt][ks] = *(const f16x8*)(src + row * RSb + ((16*q0 + 64*ks) ^ ((row & SWA) << 4)));
    }
}

// GEMM: A (regs) x W[N][K] (global f16) -> relu -> LDS, swizzle (row&7)<<4
template <int KT, int NT>
__device__ __forceinline__ void gemm_store(const f16x8 (&A)[4][KT], char* O, int RSOb,
                                           const unsigned short* __restrict__ Wg, int K,
                                           const float* __restrict__ bias, int c0, int q0) {
#pragma unroll
    for (int nt = 0; nt < NT; ++nt) {
        f16x8 B[KT];
#pragma unroll
        for (int ks = 0; ks < KT; ++ks)
            B[ks] = *(const f16x8*)(Wg + (size_t)(16*nt + c0) * K + 8*q0 + 32*ks);
        const float bv = bias[16*nt + c0];
#pragma unroll
        for (int mt = 0; mt < 4; ++mt) {
            f32x4 acc = {0.f, 0.f, 0.f, 0.f};
#pragma unroll
            for (int ks = 0; ks < KT; ++ks) acc = mfma16(A[mt][ks], B[ks], acc);
#pragma unroll
            for (int i = 0; i < 4; ++i) {
                const f16 v = (f16)fmaxf(acc[i] + bv, 0.0f);
                const int row = 16*mt + 4*q0 + i;
                *(f16*)(O + row * RSOb + ((2*(16*nt + c0)) ^ ((row & 7) << 4))) = v;
            }
        }
    }
}

// ---- MLP body (round-10/12 proven: fragments held in regs; output indirected via sidx)
__device__ __forceinline__ void mlp_body(
    char* L, const unsigned short* WB,
    const float* __restrict__ lin0_b, const float* __restrict__ lin1_b,
    const float* __restrict__ comb0_b, const float* __restrict__ comb1_b,
    const float* __restrict__ out_w, const float* __restrict__ out_b,
    const float* __restrict__ clin0_b, const float* __restrict__ clin1_b,
    const float* __restrict__ cout_w, const float* __restrict__ cout_b,
    const f16x8 (&A0)[4][1], const f16x8 (&AF)[4], const f16x8 (&AC)[4][1],
    int c0, int q0, int lane, float* __restrict__ out, int ptbase,
    const int* __restrict__ sidx, int use_idx) {
    const unsigned short* W0  = WB;
    const unsigned short* W1  = WB + 2048;
    const unsigned short* WC0 = WB + 6144;
    const unsigned short* WC1 = WB + 18432;
    const unsigned short* WL0 = WB + 34816;
    const unsigned short* WL1 = WB + 36864;

    gemm_store<1, 4>(A0, L + 4096, 128, W0, 32, lin0_b, c0, q0);
    LDS_FENCE();
    {
        f16x8 A[4][2];
        ldA<2, 7>(A, L + 4096, 128, c0, q0);
        LDS_FENCE();
        gemm_store<2, 4>(A, L, 128, W1, 64, lin1_b, c0, q0);
    }
    LDS_FENCE();
    {
        f16x8 A[4][3];
#pragma unroll
        for (int mt = 0; mt < 4; ++mt) {
            const int row = 16*mt + c0;
#pragma unroll
            for (int ks = 0; ks < 2; ++ks)
                A[mt][ks] = *(const f16x8*)(L + row * 128 + ((16*q0 + 64*ks) ^ ((row & 7) << 4)));
            A[mt][2] = AF[mt];
        }
        LDS_FENCE();
        gemm_store<3, 8>(A, L, 256, WC0, 96, comb0_b, c0, q0);
    }
    LDS_FENCE();
    float part[16];
#pragma unroll
    for (int r = 0; r < 16; ++r) part[r] = 0.f;
    {
        f16x8 A[4][4];
        ldA<4, 7>(A, L, 256, c0, q0);
        LDS_FENCE();
#pragma unroll
        for (int nt = 0; nt < 8; ++nt) {
            f16x8 B[4];
#pragma unroll
            for (int ks = 0; ks < 4; ++ks)
                B[ks] = *(const f16x8*)(WC1 + (size_t)(16*nt + c0) * 128 + 8*q0 + 32*ks);
            const float bv = comb1_b[16*nt + c0];
            const float wo = out_w[16*nt + c0];
#pragma unroll
            for (int mt = 0; mt < 4; ++mt) {
                f32x4 acc = {0.f, 0.f, 0.f, 0.f};
#pragma unroll
                for (int ks = 0; ks < 4; ++ks) acc = mfma16(A[mt][ks], B[ks], acc);
#pragma unroll
                for (int i = 0; i < 4; ++i)
                    part[4*mt + i] += wo * fmaxf(acc[i] + bv, 0.0f);
            }
        }
    }
    LDS_FENCE();
    gemm_store<1, 4>(AC, L + 4096, 128, WL0, 32, clin0_b, c0, q0);
    LDS_FENCE();
    float pc0[16], pc1[16], pc2[16];
#pragma unroll
    for (int r = 0; r < 16; ++r) { pc0[r] = 0.f; pc1[r] = 0.f; pc2[r] = 0.f; }
    {
        f16x8 A[4][2];
        ldA<2, 7>(A, L + 4096, 128, c0, q0);
        LDS_FENCE();
#pragma unroll
        for (int nt = 0; nt < 4; ++nt) {
            f16x8 B[2];
#pragma unroll
            for (int ks = 0; ks < 2; ++ks)
                B[ks] = *(const f16x8*)(WL1 + (size_t)(16*nt + c0) * 64 + 8*q0 + 32*ks);
            const float bv  = clin1_b[16*nt + c0];
            const float cw0 = cout_w[16*nt + c0];
            const float cw1 = cout_w[64 + 16*nt + c0];
            const float cw2 = cout_w[128 + 16*nt + c0];
#pragma unroll
            for (int mt = 0; mt < 4; ++mt) {
                f32x4 acc = {0.f, 0.f, 0.f, 0.f};
#pragma unroll
                for (int ks = 0; ks < 2; ++ks) acc = mfma16(A[mt][ks], B[ks], acc);
#pragma unroll
                for (int i = 0; i < 4; ++i) {
                    const float hv = fmaxf(acc[i] + bv, 0.0f);
                    pc0[4*mt+i] += cw0 * hv;
                    pc1[4*mt+i] += cw1 * hv;
                    pc2[4*mt+i] += cw2 * hv;
                }
            }
        }
    }
#pragma unroll
    for (int mt = 0; mt < 4; ++mt)
#pragma unroll
        for (int i = 0; i < 4; ++i) {
            const int r = 4*mt + i;
            const int row = 16*mt + 4*q0 + i;
            float4 v; v.x = pc0[r]; v.y = pc1[r]; v.z = pc2[r]; v.w = part[r];
            *(float4*)(L + row * 256 + ((c0 * 16) ^ ((row & 7) << 4))) = v;
        }
    LDS_FENCE();
    {
        float4 s; s.x = 0.f; s.y = 0.f; s.z = 0.f; s.w = 0.f;
#pragma unroll
        for (int c = 0; c < 16; ++c) {
            float4 v = *(const float4*)(L + lane * 256 + ((c * 16) ^ ((lane & 7) << 4)));
            s.x += v.x; s.y += v.y; s.z += v.z; s.w += v.w;
        }
        float4 o;
        o.x = 1.0f / (1.0f + __expf(-(s.x + cout_b[0])));
        o.y = 1.0f / (1.0f + __expf(-(s.y + cout_b[1])));
        o.z = 1.0f / (1.0f + __expf(-(s.z + cout_b[2])));
        o.w = s.w + out_b[0];
        const int orow = use_idx ? sidx[ptbase + lane] : (ptbase + lane);
        *(float4*)(out + 4 * (size_t)orow) = o;
    }
}

// ---- fused tile body (round-10/12 proven: 3 gathers upfront, fragments held)
__device__ __forceinline__ void fused_tile(
    const float* __restrict__ pts, const unsigned short* __restrict__ ws,
    const float* lin0_b, const float* lin1_b, const float* comb0_b, const float* comb1_b,
    const float* out_w, const float* out_b, const float* clin0_b, const float* clin1_b,
    const float* cout_w, const float* cout_b, float* out,
    char* L, int pbase, int lane, int c0, int q0,
    const int* __restrict__ sidx, int use_idx) {
    const unsigned short* WB = ws + WBOFF;
    gather3<3>(ws + PXY_C, ws + PXZ_C, ws + PYZ_C, 128, pts, pbase, lane, L);
    gather3<3>(ws + PXY_F, ws + PXZ_F, ws + PYZ_F, 512, pts, pbase, lane, L + 12288);
    LDS_FENCE();
    f16x8 A0[4][1], AC[4][1], AF[4];
#pragma unroll
    for (int mt = 0; mt < 4; ++mt) {
        const int row = 16*mt + c0;
        A0[mt][0] = *(const f16x8*)(L + row * 64 + ((16*q0) ^ ((row & 3) << 4)));
        AF[mt]    = *(const f16x8*)(L + 12288 + row * 64 + ((16*q0) ^ ((row & 3) << 4)));
    }
    LDS_FENCE();
    gather3<3>(ws + PCXY, ws + PCXZ, ws + PCYZ, 256, pts, pbase, lane, L + 12288);
    LDS_FENCE();
#pragma unroll
    for (int mt = 0; mt < 4; ++mt) {
        const int row = 16*mt + c0;
        AC[mt][0] = *(const f16x8*)(L + 12288 + row * 64 + ((16*q0) ^ ((row & 3) << 4)));
    }
    LDS_FENCE();
    mlp_body(L, WB, lin0_b, lin1_b, comb0_b, comb1_b, out_w, out_b,
             clin0_b, clin1_b, cout_w, cout_b, A0, AF, AC, c0, q0, lane,
             out, pbase, sidx, use_idx);
}

// ---- main kernel: 4 waves/block (64 KB LDS), sorted points, XCD-chunked blocks.
__global__ __launch_bounds__(256) void decoder_sorted(
    const float* __restrict__ sxyz, const unsigned short* __restrict__ ws,
    const float* __restrict__ lin0_b, const float* __restrict__ lin1_b,
    const float* __restrict__ comb0_b, const float* __restrict__ comb1_b,
    const float* __restrict__ out_w, const float* __restrict__ out_b,
    const float* __restrict__ clin0_b, const float* __restrict__ clin1_b,
    const float* __restrict__ cout_w, const float* __restrict__ cout_b,
    float* __restrict__ out, const int* __restrict__ sidx) {
    __shared__ __align__(16) unsigned short lds[4][8192];   // 64 KB / block
    const int wave = threadIdx.x >> 6, lane = threadIdx.x & 63;
    const int c0 = lane & 15, q0 = lane >> 4;
    const int nblk = (N_TILES + 3) / 4;           // 3907
    const int q = nblk >> 3, r = nblk & 7;        // 488, 3
    const int xcd = blockIdx.x & 7, j = blockIdx.x >> 3;
    const int sb = (xcd < r ? xcd * (q + 1) : r * (q + 1) + (xcd - r) * q) + j;
    const int tl = sb * 4 + wave;
    if (tl >= N_TILES) return;
    fused_tile(sxyz, ws, lin0_b, lin1_b, comb0_b, comb1_b, out_w, out_b,
               clin0_b, clin1_b, cout_w, cout_b, out,
               (char*)lds[wave], tl * 64, lane, c0, q0, sidx, 1);
}

// ---- fallback (ws too small for sort region): fused on raw points, identity order.
__global__ __launch_bounds__(256) void decoder_main(
    const float* __restrict__ p, const unsigned short* __restrict__ ws,
    const float* __restrict__ lin0_b, const float* __restrict__ lin1_b,
    const float* __restrict__ comb0_b, const float* __restrict__ comb1_b,
    const float* __restrict__ out_w, const float* __restrict__ out_b,
    const float* __restrict__ clin0_b, const float* __restrict__ clin1_b,
    const float* __restrict__ cout_w, const float* __restrict__ cout_b,
    float* __restrict__ out) {
    __shared__ __align__(16) unsigned short lds[4][8192];
    const int wave = threadIdx.x >> 6, lane = threadIdx.x & 63;
    const int c0 = lane & 15, q0 = lane >> 4;
    const int tl = blockIdx.x * 4 + wave;
    if (tl >= N_TILES) return;
    fused_tile(p, ws, lin0_b, lin1_b, comb0_b, comb1_b, out_w, out_b,
               clin0_b, clin1_b, cout_w, cout_b, out,
               (char*)lds[wave], tl * 64, lane, c0, q0, nullptr, 0);
}

extern "C" void kernel_launch(void* const* d_in, const int* in_sizes, int n_in,
                              void* d_out, int out_size, void* d_ws, size_t ws_size,
                              hipStream_t stream) {
    if (ws_size < FIXED_BYTES) return;
    unsigned short* ws = (unsigned short*)d_ws;
    char* wsb = (char*)d_ws;

    transpose_all<<<4032, 256, 0, stream>>>(
        (const float*)d_in[1], (const float*)d_in[2], (const float*)d_in[3],
        (const float*)d_in[4], (const float*)d_in[5], (const float*)d_in[6],
        (const float*)d_in[7], (const float*)d_in[8], (const float*)d_in[9], ws);
    weights_all<<<160, 256, 0, stream>>>(
        (const float*)d_in[10], (const float*)d_in[12], (const float*)d_in[14],
        (const float*)d_in[16], (const float*)d_in[20], (const float*)d_in[22],
        ws + WBOFF);

    const float* p = (const float*)d_in[0];
    const float* lin0_b  = (const float*)d_in[11];
    const float* lin1_b  = (const float*)d_in[13];
    const float* comb0_b = (const float*)d_in[15];
    const float* comb1_b = (const float*)d_in[17];
    const float* out_w   = (const float*)d_in[18];
    const float* out_b   = (const float*)d_in[19];
    const float* clin0_b = (const float*)d_in[21];
    const float* clin1_b = (const float*)d_in[23];
    const float* cout_w  = (const float*)d_in[24];
    const float* cout_b  = (const float*)d_in[25];
    float* out = (float*)d_out;

    if (ws_size >= SORT_END) {
        int*   hist   = (int*)(wsb + HIST_B);
        int*   cursor = (int*)(wsb + CURS_B);
        int*   sidx   = (int*)(wsb + SIDX_B);
        float* sxyz   = (float*)(wsb + SXYZ_B);

        hipMemsetAsync(hist, 0, NBKT * sizeof(int), stream);
        hist_kernel<<<(N_PTS + 255) / 256, 256, 0, stream>>>(p, hist);
        scan_kernel<<<1, 1024, 0, stream>>>(hist, cursor);
        scatter_kernel<<<(N_PTS + 255) / 256, 256, 0, stream>>>(p, cursor, sxyz, sidx);

        decoder_sorted<<<(N_TILES + 3) / 4, 256, 0, stream>>>(sxyz, ws,
            lin0_b, lin1_b, comb0_b, comb1_b, out_w, out_b,
            clin0_b, clin1_b, cout_w, cout_b, out, sidx);
    } else {
        decoder_main<<<(N_TILES + 3) / 4, 256, 0, stream>>>(p, ws,
            lin0_b, lin1_b, comb0_b, comb1_b, out_w, out_b,
            clin0_b, clin1_b, cout_w, cout_b, out);
    }
}